// Round 1
// baseline (49.152 us; speedup 1.0000x reference)
//
#include <hip/hip_runtime.h>

// LIF membrane update, fused:
//   v_new[b,n] = ALPHA*v[b,n] + sum_i x[b,i,n]*w[i,n] - V_TH*z[b,n]
//   z_new[b,n] = (v_new[b,n] - V_TH > 0) ? 1 : 0
// Shapes: x (128,1024,512) f32, w (1024,512) f32, v,z (128,512) f32.
// Memory-bound: x = 256 MB read once; floor ~41 us @ 6.3 TB/s.

constexpr int B    = 128;
constexpr int N_IN = 1024;
constexpr int NN   = 512;
constexpr int NN4  = NN / 4;          // 128 float4 columns
constexpr float ALPHA = 1.0f - 0.05f / 10.0f;  // 0.995
constexpr float V_TH  = 2.0f;

// Block = 256 threads: handles one batch b and a slab of 64 n (16 float4 cols).
// Thread (g = t&15, c = t>>4): accumulates i in [64c, 64c+64) for column g.
// LDS tree-reduce across the 16 i-chunks, then 16 threads finalize.
__global__ __launch_bounds__(256) void lif_fused(
    const float4* __restrict__ x4,
    const float4* __restrict__ w4,
    const float4* __restrict__ v4,
    const float4* __restrict__ z4,
    float4* __restrict__ vout4,
    float4* __restrict__ zout4)
{
    const int t    = threadIdx.x;
    const int g    = t & 15;          // float4 column within slab
    const int c    = t >> 4;          // i-chunk (0..15), 64 i's each
    const int b    = blockIdx.x >> 3; // 0..127
    const int slab = blockIdx.x & 7;  // 0..7
    const int n4   = slab * 16 + g;   // float4 column index, 0..127

    const float4* __restrict__ xp =
        x4 + (size_t)b * N_IN * NN4 + (size_t)(c * 64) * NN4 + n4;
    const float4* __restrict__ wp =
        w4 + (size_t)(c * 64) * NN4 + n4;

    float ax = 0.f, ay = 0.f, az = 0.f, aw = 0.f;
    #pragma unroll 8
    for (int ii = 0; ii < 64; ++ii) {
        float4 xv = xp[(size_t)ii * NN4];   // coalesced: 16 lanes x 16B contiguous
        float4 wv = wp[(size_t)ii * NN4];   // L2-resident (w = 2 MB, reused x128)
        ax = fmaf(xv.x, wv.x, ax);
        ay = fmaf(xv.y, wv.y, ay);
        az = fmaf(xv.z, wv.z, az);
        aw = fmaf(xv.w, wv.w, aw);
    }

    __shared__ float4 red[256];
    red[t] = make_float4(ax, ay, az, aw);
    __syncthreads();

    // Tree reduce over c (same g): partner index differs by s (= stride in c*16)
    #pragma unroll
    for (int s = 128; s >= 16; s >>= 1) {
        if (t < s) {
            float4 a = red[t], o = red[t + s];
            a.x += o.x; a.y += o.y; a.z += o.z; a.w += o.w;
            red[t] = a;
        }
        __syncthreads();
    }

    if (t < 16) {
        float4 a = red[t];                  // c==0 slot holds full sum for g=t
        const int col = slab * 16 + t;      // float4 column, 0..127
        const int idx = b * NN4 + col;
        float4 vv = v4[idx];
        float4 zz = z4[idx];
        float4 vn;
        vn.x = fmaf(ALPHA, vv.x, a.x) - V_TH * zz.x;
        vn.y = fmaf(ALPHA, vv.y, a.y) - V_TH * zz.y;
        vn.z = fmaf(ALPHA, vv.z, a.z) - V_TH * zz.z;
        vn.w = fmaf(ALPHA, vv.w, a.w) - V_TH * zz.w;
        vout4[idx] = vn;
        float4 zn;
        zn.x = (vn.x - V_TH > 0.f) ? 1.f : 0.f;
        zn.y = (vn.y - V_TH > 0.f) ? 1.f : 0.f;
        zn.z = (vn.z - V_TH > 0.f) ? 1.f : 0.f;
        zn.w = (vn.w - V_TH > 0.f) ? 1.f : 0.f;
        zout4[idx] = zn;
    }
}

extern "C" void kernel_launch(void* const* d_in, const int* in_sizes, int n_in,
                              void* d_out, int out_size, void* d_ws, size_t ws_size,
                              hipStream_t stream) {
    const float4* x = (const float4*)d_in[0];
    const float4* w = (const float4*)d_in[1];
    const float4* v = (const float4*)d_in[2];
    const float4* z = (const float4*)d_in[3];
    float4* vout = (float4*)d_out;                 // v_new: B*NN floats
    float4* zout = vout + (size_t)B * NN4;         // z_new follows flat

    lif_fused<<<dim3(B * 8), dim3(256), 0, stream>>>(x, w, v, z, vout, zout);
}

// Round 3
// 48.844 us; speedup vs baseline: 1.0063x; 1.0063x over previous
//
#include <hip/hip_runtime.h>

// LIF membrane update, fused:
//   v_new[b,n] = ALPHA*v[b,n] + sum_i x[b,i,n]*w[i,n] - V_TH*z[b,n]
//   z_new[b,n] = (v_new[b,n] - V_TH > 0) ? 1 : 0
// Shapes: x (128,1024,512) f32, w (1024,512) f32, v,z (128,512) f32.
// Memory-bound: x = 256 MB read once; floor ~41 us @ 6.3 TB/s.
//
// R2 structure (= R1 intent, compile-fixed with ext_vector_type):
//  - kernel 1 (lif_partial): block = 256 thr handles 2 batches x 64 f4-cols
//    x 128 i's. col = t&63 -> each wave-64 load is one contiguous 1024B
//    segment. c = t>>6 splits the 128-i group 4-way; LDS tree-reduce.
//    2 batches/block reuses each w load across 2 FMA chains (-25% VMEM ops).
//    x loads non-temporal (stream-once; keep 2MB w resident in L2).
//    Grid = 64 bpairs x 2 slabs x 8 igroups = 1024 blocks (16 waves/CU).
//  - kernel 2 (lif_finalize): sums the 8 igroup partials, applies LIF update.

typedef float f32x4 __attribute__((ext_vector_type(4)));

constexpr int B    = 128;
constexpr int N_IN = 1024;
constexpr int NN   = 512;
constexpr int NN4  = NN / 4;          // 128 float4 columns
constexpr float ALPHA = 1.0f - 0.05f / 10.0f;  // 0.995
constexpr float V_TH  = 2.0f;

__global__ __launch_bounds__(256) void lif_partial(
    const f32x4* __restrict__ x4,
    const f32x4* __restrict__ w4,
    f32x4* __restrict__ part)   // [8 igroups][B][NN4]
{
    const int t    = threadIdx.x;
    const int g    = t & 63;            // float4 column within slab (64 wide)
    const int c    = t >> 6;            // i-subchunk (0..3), 32 i's each
    const int sub  = blockIdx.x & 15;   // 16 subtiles = 2 slabs x 8 igroups
    const int bp   = blockIdx.x >> 4;   // batch pair 0..63
    const int slab = sub & 1;
    const int ig   = sub >> 1;          // 0..7, 128 i's each

    const int b0  = bp * 2;
    const int col = slab * 64 + g;      // float4 column 0..127
    const int i0  = ig * 128 + c * 32;

    const f32x4* __restrict__ xp0 =
        x4 + ((size_t)b0 * N_IN + i0) * NN4 + col;
    const f32x4* __restrict__ xp1 = xp0 + (size_t)N_IN * NN4;
    const f32x4* __restrict__ wp  = w4 + (size_t)i0 * NN4 + col;

    f32x4 a0 = {0.f, 0.f, 0.f, 0.f};
    f32x4 a1 = {0.f, 0.f, 0.f, 0.f};
    #pragma unroll 8
    for (int ii = 0; ii < 32; ++ii) {
        f32x4 wv  = wp[(size_t)ii * NN4];                               // L2-hit
        f32x4 xv0 = __builtin_nontemporal_load(&xp0[(size_t)ii * NN4]); // HBM stream
        f32x4 xv1 = __builtin_nontemporal_load(&xp1[(size_t)ii * NN4]);
        a0 += xv0 * wv;
        a1 += xv1 * wv;
    }

    __shared__ f32x4 red0[256];
    __shared__ f32x4 red1[256];
    red0[t] = a0;
    red1[t] = a1;
    __syncthreads();

    // Tree reduce over c (4 partials per column, partner stride 64 in t)
    if (t < 128) {
        red0[t] += red0[t + 128];
        red1[t] += red1[t + 128];
    }
    __syncthreads();
    if (t < 64) {
        f32x4 s0 = red0[t] + red0[t + 64];
        f32x4 s1 = red1[t] + red1[t + 64];
        const int cidx = slab * 64 + t;
        part[((size_t)ig * B + b0)     * NN4 + cidx] = s0;
        part[((size_t)ig * B + b0 + 1) * NN4 + cidx] = s1;
    }
}

__global__ __launch_bounds__(256) void lif_finalize(
    const f32x4* __restrict__ part,  // [8][B][NN4]
    const f32x4* __restrict__ v4,
    const f32x4* __restrict__ z4,
    f32x4* __restrict__ vout4,
    f32x4* __restrict__ zout4)
{
    const int idx = blockIdx.x * 256 + threadIdx.x;   // over B*NN4 = 16384
    if (idx >= B * NN4) return;
    f32x4 s = part[idx];
    #pragma unroll
    for (int igr = 1; igr < 8; ++igr)
        s += part[(size_t)igr * B * NN4 + idx];
    f32x4 vv = v4[idx];
    f32x4 zz = z4[idx];
    f32x4 vn = ALPHA * vv + s - V_TH * zz;
    vout4[idx] = vn;
    f32x4 zn;
    zn.x = (vn.x - V_TH > 0.f) ? 1.f : 0.f;
    zn.y = (vn.y - V_TH > 0.f) ? 1.f : 0.f;
    zn.z = (vn.z - V_TH > 0.f) ? 1.f : 0.f;
    zn.w = (vn.w - V_TH > 0.f) ? 1.f : 0.f;
    zout4[idx] = zn;
}

extern "C" void kernel_launch(void* const* d_in, const int* in_sizes, int n_in,
                              void* d_out, int out_size, void* d_ws, size_t ws_size,
                              hipStream_t stream) {
    const f32x4* x = (const f32x4*)d_in[0];
    const f32x4* w = (const f32x4*)d_in[1];
    const f32x4* v = (const f32x4*)d_in[2];
    const f32x4* z = (const f32x4*)d_in[3];
    f32x4* vout = (f32x4*)d_out;                 // v_new: B*NN floats
    f32x4* zout = vout + (size_t)B * NN4;        // z_new follows flat
    f32x4* part = (f32x4*)d_ws;                  // 8*B*NN4 f32x4 = 2 MB

    lif_partial<<<dim3(64 * 16), dim3(256), 0, stream>>>(x, w, part);
    lif_finalize<<<dim3((B * NN4 + 255) / 256), dim3(256), 0, stream>>>(
        part, v, z, vout, zout);
}